// Round 9
// baseline (166.474 us; speedup 1.0000x reference)
//
#include <hip/hip_runtime.h>

#define HD 257
#define WD 257
#define COUT 64
#define LROW 17       // accum LDS row stride (floats): breaks x*16 bank pattern
#define GPTS 64       // gather: points per block

typedef unsigned int uint;
typedef unsigned short ushort;
typedef short short8 __attribute__((ext_vector_type(8)));
typedef float f32x4 __attribute__((ext_vector_type(4)));

// f32 -> bf16 RNE
__device__ __forceinline__ uint pack_bf16(float a, float b) {
    uint ua = __float_as_uint(a), ub = __float_as_uint(b);
    ua += 0x7fffu + ((ua >> 16) & 1u);
    ub += 0x7fffu + ((ub >> 16) & 1u);
    return (ua >> 16) | (ub & 0xffff0000u);
}
__device__ __forceinline__ unsigned short bf16_1(float a) {
    uint ua = __float_as_uint(a);
    ua += 0x7fffu + ((ua >> 16) & 1u);
    return (unsigned short)(ua >> 16);
}

// K1: scan-based accumulate. Block (g, b) owns rows y0=2g, y0+1 of batch b.
// Scans the batch's 32768 points (512 KB, coalesced, L2-resident across blocks),
// selects its rows' points (~0.8%), accumulates f32 in LDS, emits bf16 voxel rows.
// No global atomics anywhere.
__global__ __launch_bounds__(256) void accum_kernel(
    const float* __restrict__ xyzp,
    const float* __restrict__ feat,
    uint* __restrict__ voxn,       // [S][8] normalized bf16 pairs
    int N) {
    __shared__ float l[2 * WD * LROW];  // 34952 B -> 4 blocks/CU
    const int tid = threadIdx.x;
    const int b = blockIdx.y;
    const int y0 = blockIdx.x * 2;      // 129 groups: last has only row 256
    for (int i = tid; i < 2 * WD * LROW; i += 256) l[i] = 0.0f;
    __syncthreads();

    const float4* xp = reinterpret_cast<const float4*>(xyzp) + (size_t)b * N;
    const float* fb = feat + (size_t)b * N * 14;
    for (int i = tid; i < N; i += 256) {
        float4 v = xp[i];
        int y = (int)fminf(fmaxf(rintf(v.y * 256.0f), 0.0f), 256.0f);
        int dr = y - y0;
        if ((uint)dr < 2u) {   // rare (~0.8%): predicated body
            int x = (int)fminf(fmaxf(rintf(v.x * 256.0f), 0.0f), 256.0f);
            float* cell = l + (dr * WD + x) * LROW;
            atomicAdd(&cell[0], v.w);
            atomicAdd(&cell[1], 1.0f - v.w);
            const float2* f2 = reinterpret_cast<const float2*>(fb + (size_t)i * 14);
#pragma unroll
            for (int j = 0; j < 7; ++j) {
                float2 fv = f2[j];
                atomicAdd(&cell[2 + 2 * j], fv.x);
                atomicAdd(&cell[3 + 2 * j], fv.y);
            }
        }
    }
    __syncthreads();

    int nrows = (y0 + 1 < HD) ? 2 : 1;
    for (int i = tid; i < nrows * WD; i += 256) {
        int r = (i >= WD) ? 1 : 0;
        int x = i - r * WD;
        const float* c = l + (r * WD + x) * LROW;
        float inv = __builtin_amdgcn_rcpf(fmaxf(c[0] + c[1], 1.0f));
        uint o[8];
#pragma unroll
        for (int j = 0; j < 8; ++j)
            o[j] = pack_bf16(c[2 * j] * inv, c[2 * j + 1] * inv);
        uint4* op = reinterpret_cast<uint4*>(
            voxn + ((size_t)(b * HD + y0 + r) * WD + x) * 8);
        op[0] = make_uint4(o[0], o[1], o[2], o[3]);
        op[1] = make_uint4(o[4], o[5], o[6], o[7]);
    }
}

// K2: 64 points / 256 thr (4 waves). A[64][K=160] bf16 in LDS (336 B row).
// Wave w computes cols w*16..w*16+15 over all 64 rows. k = (dy*3+dx)*16 + c.
__global__ __launch_bounds__(256) void gather_mfma_kernel(
    const float* __restrict__ xyzp,
    const uint* __restrict__ voxn,   // [S][8] normalized bf16 pairs
    const float* __restrict__ W,     // [9][16][64] f32 = [144][64]
    const float* __restrict__ bias,
    float* __restrict__ out, int logN) {
    __shared__ __align__(16) char sA[GPTS * 336];  // 21504 B
    __shared__ int sCell[GPTS];
    __shared__ uint sYX[GPTS];

    const int tid = threadIdx.x;
    const int lane = tid & 63;
    const int w = tid >> 6;
    const int p0 = blockIdx.x * GPTS;
    const int hi = lane >> 4;
    const int lo = lane & 15;

    // per-point data computed ONCE (threads 0..63)
    if (tid < GPTS) {
        float4 v = reinterpret_cast<const float4*>(xyzp)[p0 + tid];
        int y = (int)fminf(fmaxf(rintf(v.y * 256.0f), 0.0f), 256.0f);
        int x = (int)fminf(fmaxf(rintf(v.x * 256.0f), 0.0f), 256.0f);
        int b = (p0 + tid) >> logN;
        sCell[tid] = (b * HD + y) * WD + x;
        sYX[tid] = ((uint)y << 16) | (uint)x;
    }

    // B fragments (issued before barrier; latency overlaps)
    short8 bfrag[5];
    float bv = bias[w * 16 + lo];
#pragma unroll
    for (int s = 0; s < 5; ++s) {
        int kbase = s * 32 + hi * 8;
        short8 f;
#pragma unroll
        for (int j = 0; j < 8; ++j) {
            int k = kbase + j;
            float wv = (k < 144) ? W[(size_t)k * 64 + w * 16 + lo] : 0.0f;
            f[j] = (short)bf16_1(wv);
        }
        bfrag[s] = f;
    }
    __syncthreads();

    // A build: 18 chunks/point (3 dy-segs x 3 kx x 2 halves of 16 B)
    for (int idx = tid; idx < GPTS * 18; idx += 256) {
        int i = idx / 18;
        int r = idx - i * 18;
        int seg = r / 6;          // dy+1
        int h = r - seg * 6;
        int kx = h >> 1;
        int half = h & 1;
        uint yx = sYX[i];
        int y = (int)(yx >> 16), x = (int)(yx & 0xffffu);
        int ny = y + seg - 1, nx = x + kx - 1;
        uint4 val = make_uint4(0, 0, 0, 0);
        if ((uint)ny <= 256u && (uint)nx <= 256u) {
            size_t ncell = (size_t)sCell[i] + (size_t)((seg - 1) * WD + (kx - 1));
            val = *reinterpret_cast<const uint4*>(
                reinterpret_cast<const char*>(voxn) + ncell * 32 + (size_t)half * 16);
        }
        *reinterpret_cast<uint4*>(sA + i * 336 + (seg * 3 + kx) * 32 + half * 16) = val;
    }
    // zero-pad k in [144,160)
    if (tid < GPTS * 2) {
        int i = tid >> 1, h = tid & 1;
        *reinterpret_cast<uint4*>(sA + i * 336 + 288 + h * 16) = make_uint4(0, 0, 0, 0);
    }
    __syncthreads();

    f32x4 acc[4];
#pragma unroll
    for (int mt = 0; mt < 4; ++mt) acc[mt] = (f32x4){bv, bv, bv, bv};

#pragma unroll
    for (int mt = 0; mt < 4; ++mt) {
        const char* abase = sA + (mt * 16 + lo) * 336 + hi * 16;
#pragma unroll
        for (int s = 0; s < 5; ++s) {
            short8 a = *reinterpret_cast<const short8*>(abase + s * 64);
            acc[mt] = __builtin_amdgcn_mfma_f32_16x16x32_bf16(a, bfrag[s], acc[mt], 0, 0, 0);
        }
    }

    // store: D col = lane&15, row = hi*4 + reg (m89-verified)
#pragma unroll
    for (int mt = 0; mt < 4; ++mt)
#pragma unroll
        for (int r = 0; r < 4; ++r) {
            int row = mt * 16 + hi * 4 + r;
            out[(size_t)(p0 + row) * 64 + w * 16 + lo] = acc[mt][r];
        }
}

extern "C" void kernel_launch(void* const* d_in, const int* in_sizes, int n_in,
                              void* d_out, int out_size, void* d_ws, size_t ws_size,
                              hipStream_t stream) {
    const float* xyzp = (const float*)d_in[0];
    const float* feat = (const float*)d_in[1];
    const float* W    = (const float*)d_in[2];
    const float* bias = (const float*)d_in[3];
    float* out = (float*)d_out;

    const int BN = in_sizes[0] / 4;  // 262144
    const int B = 8;
    const int N = BN / B;            // 32768
    int logN = 0;
    while ((1 << logN) < N) ++logN;  // 15

    // ws: voxn only == 16.9 MB
    uint* voxn = (uint*)d_ws;
    (void)ws_size;

    dim3 agrid((HD + 1) / 2, B);     // 129 x 8 row-pair blocks
    accum_kernel<<<agrid, 256, 0, stream>>>(xyzp, feat, voxn, N);
    gather_mfma_kernel<<<BN / GPTS, 256, 0, stream>>>(xyzp, voxn, W, bias, out, logN);
}

// Round 10
// 74.021 us; speedup vs baseline: 2.2490x; 2.2490x over previous
//
#include <hip/hip_runtime.h>

#define HD 257
#define WD 257
#define NB (8 * HD)   // 2056 (b,y)-row buckets
#define CAP 384       // max points per row bucket (lambda~128, 22 sigma headroom)
#define COUT 64
#define LROW 17       // accum LDS row stride (floats): breaks x*16 bank pattern
#define RPB 2         // accum: rows per block
#define GPTS 64       // gather: points per block
#define BPTS 1024     // bin: points per block (4/thread)

typedef unsigned int uint;
typedef unsigned short ushort;
typedef short short8 __attribute__((ext_vector_type(8)));
typedef float f32x4 __attribute__((ext_vector_type(4)));

// f32 -> bf16 RNE
__device__ __forceinline__ uint pack_bf16(float a, float b) {
    uint ua = __float_as_uint(a), ub = __float_as_uint(b);
    ua += 0x7fffu + ((ua >> 16) & 1u);
    ub += 0x7fffu + ((ub >> 16) & 1u);
    return (ua >> 16) | (ub & 0xffff0000u);
}
__device__ __forceinline__ unsigned short bf16_1(float a) {
    uint ua = __float_as_uint(a);
    ua += 0x7fffu + ((ua >> 16) & 1u);
    return (unsigned short)(ua >> 16);
}

// K0: zero the 2056 row counters
__global__ void zero_cnt_kernel(uint* __restrict__ cnt) {
    int i = blockIdx.x * blockDim.x + threadIdx.x;
    if (i < NB) cnt[i] = 0u;
}

// K1: bin-v3 — per-batch LDS histogram. Block (chunk, b) owns 1024 points of
// batch b. LDS-atomic rank capture, ONE global atomic per nonzero bucket
// (~252/block, 64k total vs 262k same-line RMWs before), then 2B pidx writes.
__global__ __launch_bounds__(256) void bin_kernel(
    const float* __restrict__ xyzp,
    uint* __restrict__ cnt,      // [NB]
    ushort* __restrict__ pidx,   // [NB][CAP] local point idx within batch
    int N) {
    __shared__ uint hist[HD];
    __shared__ uint base[HD];
    const int tid = threadIdx.x;
    const int b = blockIdx.y;
    const int p0 = blockIdx.x * BPTS;   // offset within batch

    for (int i = tid; i < HD; i += 256) hist[i] = 0u;
    __syncthreads();

    const float4* xp = reinterpret_cast<const float4*>(xyzp) + (size_t)b * N;
    uint rec[BPTS / 256];
#pragma unroll
    for (int k = 0; k < BPTS / 256; ++k) {
        int i = p0 + tid + k * 256;
        float4 v = xp[i];
        int y = (int)fminf(fmaxf(rintf(v.y * 256.0f), 0.0f), 256.0f);
        uint r = atomicAdd(&hist[y], 1u);       // LDS: rank within block
        rec[k] = (uint)y | (r << 9);
    }
    __syncthreads();

    for (int y = tid; y < HD; y += 256) {
        uint h = hist[y];
        base[y] = h ? atomicAdd(&cnt[b * HD + y], h) : 0u;  // global: 1 per bucket
    }
    __syncthreads();

#pragma unroll
    for (int k = 0; k < BPTS / 256; ++k) {
        int y = rec[k] & 511;
        uint slot = base[y] + (rec[k] >> 9);
        if (slot < CAP)
            pidx[(size_t)(b * HD + y) * CAP + slot] = (ushort)(p0 + tid + k * 256);
    }
}

// K2: accum-v2 — RPB rows/block; fetch point data directly, f32 LDS accumulate,
// normalize (count = ch0+ch1), emit bf16 voxel rows.
__global__ __launch_bounds__(256) void accum_kernel(
    const uint* __restrict__ cnt,
    const ushort* __restrict__ pidx,
    const float* __restrict__ xyzp,
    const float* __restrict__ feat,
    uint* __restrict__ voxn,       // [S][8] normalized bf16 pairs
    int logN) {
    __shared__ float l[RPB * WD * LROW];  // 34952 B -> 4 blocks/CU
    const int tid = threadIdx.x;
    const int bucket0 = blockIdx.x * RPB;
    for (int i = tid; i < RPB * WD * LROW; i += 256) l[i] = 0.0f;
    __syncthreads();

    uint n0 = min(cnt[bucket0], (uint)CAP);
    uint n1 = min(cnt[bucket0 + 1], (uint)CAP);
    uint ntot = n0 + n1;
    for (uint s = tid; s < ntot; s += 256) {
        int r = (s >= n0) ? 1 : 0;
        uint slot = s - (r ? n0 : 0u);
        int bucket = bucket0 + r;
        int b = bucket / HD;              // const-div -> magic mul
        uint lp = pidx[(size_t)bucket * CAP + slot];
        int p = (b << logN) + (int)lp;
        float4 v = reinterpret_cast<const float4*>(xyzp)[p];
        int x = (int)fminf(fmaxf(rintf(v.x * 256.0f), 0.0f), 256.0f);
        float* cell = l + (r * WD + x) * LROW;
        atomicAdd(&cell[0], v.w);
        atomicAdd(&cell[1], 1.0f - v.w);
        const float2* f2 = reinterpret_cast<const float2*>(feat + (size_t)p * 14);
#pragma unroll
        for (int j = 0; j < 7; ++j) {
            float2 fv = f2[j];
            atomicAdd(&cell[2 + 2 * j], fv.x);
            atomicAdd(&cell[3 + 2 * j], fv.y);
        }
    }
    __syncthreads();

    for (int i = tid; i < RPB * WD; i += 256) {
        int r = i / WD;
        int x = i - r * WD;
        const float* c = l + (r * WD + x) * LROW;
        float inv = __builtin_amdgcn_rcpf(fmaxf(c[0] + c[1], 1.0f));
        uint o[8];
#pragma unroll
        for (int j = 0; j < 8; ++j)
            o[j] = pack_bf16(c[2 * j] * inv, c[2 * j + 1] * inv);
        uint4* op = reinterpret_cast<uint4*>(voxn + ((size_t)(bucket0 + r) * WD + x) * 8);
        op[0] = make_uint4(o[0], o[1], o[2], o[3]);
        op[1] = make_uint4(o[4], o[5], o[6], o[7]);
    }
}

// K3: 64 points / 256 thr (4 waves). A[64][K=160] bf16 in LDS (336 B row).
// Wave w computes cols w*16..w*16+15 over all 64 rows. k = (dy*3+dx)*16 + c.
__global__ __launch_bounds__(256) void gather_mfma_kernel(
    const float* __restrict__ xyzp,
    const uint* __restrict__ voxn,   // [S][8] normalized bf16 pairs
    const float* __restrict__ W,     // [9][16][64] f32 = [144][64]
    const float* __restrict__ bias,
    float* __restrict__ out, int logN) {
    __shared__ __align__(16) char sA[GPTS * 336];  // 21504 B
    __shared__ int sCell[GPTS];
    __shared__ uint sYX[GPTS];

    const int tid = threadIdx.x;
    const int lane = tid & 63;
    const int w = tid >> 6;
    const int p0 = blockIdx.x * GPTS;
    const int hi = lane >> 4;
    const int lo = lane & 15;

    // per-point data computed ONCE (threads 0..63)
    if (tid < GPTS) {
        float4 v = reinterpret_cast<const float4*>(xyzp)[p0 + tid];
        int y = (int)fminf(fmaxf(rintf(v.y * 256.0f), 0.0f), 256.0f);
        int x = (int)fminf(fmaxf(rintf(v.x * 256.0f), 0.0f), 256.0f);
        int b = (p0 + tid) >> logN;
        sCell[tid] = (b * HD + y) * WD + x;
        sYX[tid] = ((uint)y << 16) | (uint)x;
    }

    // B fragments (issued before barrier; latency overlaps)
    short8 bfrag[5];
    float bv = bias[w * 16 + lo];
#pragma unroll
    for (int s = 0; s < 5; ++s) {
        int kbase = s * 32 + hi * 8;
        short8 f;
#pragma unroll
        for (int j = 0; j < 8; ++j) {
            int k = kbase + j;
            float wv = (k < 144) ? W[(size_t)k * 64 + w * 16 + lo] : 0.0f;
            f[j] = (short)bf16_1(wv);
        }
        bfrag[s] = f;
    }
    __syncthreads();

    // A build: 18 chunks/point (3 dy-segs x 3 kx x 2 halves of 16 B)
    for (int idx = tid; idx < GPTS * 18; idx += 256) {
        int i = idx / 18;
        int r = idx - i * 18;
        int seg = r / 6;          // dy+1
        int h = r - seg * 6;
        int kx = h >> 1;
        int half = h & 1;
        uint yx = sYX[i];
        int y = (int)(yx >> 16), x = (int)(yx & 0xffffu);
        int ny = y + seg - 1, nx = x + kx - 1;
        uint4 val = make_uint4(0, 0, 0, 0);
        if ((uint)ny <= 256u && (uint)nx <= 256u) {
            size_t ncell = (size_t)sCell[i] + (size_t)((seg - 1) * WD + (kx - 1));
            val = *reinterpret_cast<const uint4*>(
                reinterpret_cast<const char*>(voxn) + ncell * 32 + (size_t)half * 16);
        }
        *reinterpret_cast<uint4*>(sA + i * 336 + (seg * 3 + kx) * 32 + half * 16) = val;
    }
    // zero-pad k in [144,160)
    if (tid < GPTS * 2) {
        int i = tid >> 1, h = tid & 1;
        *reinterpret_cast<uint4*>(sA + i * 336 + 288 + h * 16) = make_uint4(0, 0, 0, 0);
    }
    __syncthreads();

    f32x4 acc[4];
#pragma unroll
    for (int mt = 0; mt < 4; ++mt) acc[mt] = (f32x4){bv, bv, bv, bv};

#pragma unroll
    for (int mt = 0; mt < 4; ++mt) {
        const char* abase = sA + (mt * 16 + lo) * 336 + hi * 16;
#pragma unroll
        for (int s = 0; s < 5; ++s) {
            short8 a = *reinterpret_cast<const short8*>(abase + s * 64);
            acc[mt] = __builtin_amdgcn_mfma_f32_16x16x32_bf16(a, bfrag[s], acc[mt], 0, 0, 0);
        }
    }

    // store: D col = lane&15, row = hi*4 + reg (m89-verified)
#pragma unroll
    for (int mt = 0; mt < 4; ++mt)
#pragma unroll
        for (int r = 0; r < 4; ++r) {
            int row = mt * 16 + hi * 4 + r;
            out[(size_t)(p0 + row) * 64 + w * 16 + lo] = acc[mt][r];
        }
}

extern "C" void kernel_launch(void* const* d_in, const int* in_sizes, int n_in,
                              void* d_out, int out_size, void* d_ws, size_t ws_size,
                              hipStream_t stream) {
    const float* xyzp = (const float*)d_in[0];
    const float* feat = (const float*)d_in[1];
    const float* W    = (const float*)d_in[2];
    const float* bias = (const float*)d_in[3];
    float* out = (float*)d_out;

    const int BN = in_sizes[0] / 4;  // 262144
    const int B = 8;
    const int N = BN / B;            // 32768
    int logN = 0;
    while ((1 << logN) < N) ++logN;  // 15

    // ws layout: cnt | pidx | voxn == 18.5 MB total
    uint* cnt = (uint*)d_ws;                               // 8224 B
    ushort* pidx = (ushort*)(cnt + NB);                    // NB*CAP*2 = 1.58 MB
    uint* voxn = (uint*)(pidx + (size_t)NB * CAP);         // S*32 = 16.9 MB
    (void)ws_size;

    zero_cnt_kernel<<<(NB + 255) / 256, 256, 0, stream>>>(cnt);
    dim3 bgrid(N / BPTS, B);         // 32 x 8 blocks
    bin_kernel<<<bgrid, 256, 0, stream>>>(xyzp, cnt, pidx, N);
    accum_kernel<<<NB / RPB, 256, 0, stream>>>(cnt, pidx, xyzp, feat, voxn, logN);
    gather_mfma_kernel<<<BN / GPTS, 256, 0, stream>>>(xyzp, voxn, W, bias, out, logN);
}